// Round 7
// baseline (145.216 us; speedup 1.0000x reference)
//
#include <hip/hip_runtime.h>
#include <hip/hip_bf16.h>
#include <math.h>

#define B_ 4
#define S_ 2048
#define D_ 256
#define H_ 8
#define HD_ 32
#define DFF_ 512

typedef __attribute__((ext_vector_type(8))) short bf16x8;
typedef __attribute__((ext_vector_type(4))) float f32x4;

__device__ inline short f2bf(float f) {
  union { float f; unsigned u; } x; x.f = f;
  unsigned r = (x.u + 0x7FFFu + ((x.u >> 16) & 1u)) >> 16;
  return (short)r;
}
__device__ inline float bf2f(short s) {
  union { unsigned u; float f; } x; x.u = ((unsigned)(unsigned short)s) << 16;
  return x.f;
}
__device__ inline unsigned cvt_pk_bf16(float a, float b) {
  unsigned r;
  asm("v_cvt_pk_bf16_f32 %0, %1, %2" : "=v"(r) : "v"(a), "v"(b));
  return r;
}
__device__ inline float exp2v(float x) {
  float r;
  asm("v_exp_f32 %0, %1" : "=v"(r) : "v"(x));
  return r;
}

// ---------------- merged f32->bf16 conversion: tokens + 4 weight matrices
__global__ __launch_bounds__(256) void cvt_all(const float* __restrict__ tok, const float* __restrict__ wq,
                                               const float* __restrict__ wo, const float* __restrict__ w1,
                                               const float* __restrict__ w2,
                                               short* __restrict__ dtok, short* __restrict__ dwq,
                                               short* __restrict__ dwo, short* __restrict__ dw1,
                                               short* __restrict__ dw2) {
  int blk = blockIdx.x;
  const float* src; short* dst; int base;
  if (blk < 2048)      { src = tok; dst = dtok; base = blk; }
  else if (blk < 2240) { src = wq;  dst = dwq;  base = blk - 2048; }
  else if (blk < 2304) { src = wo;  dst = dwo;  base = blk - 2240; }
  else if (blk < 2432) { src = w1;  dst = dw1;  base = blk - 2304; }
  else                 { src = w2;  dst = dw2;  base = blk - 2432; }
  int i = (base * 256 + threadIdx.x) * 4;
  float4 v = *(const float4*)(src + i);
  short4 s; s.x = f2bf(v.x); s.y = f2bf(v.y); s.z = f2bf(v.z); s.w = f2bf(v.w);
  *(short4*)(dst + i) = s;
}

// ---------------- bf16 MFMA GEMM, BM=128, BN=64:  C = A * W^T + bias
// MODE 1: SiLU -> bf16 ; MODE 2: QKV scatter (Q scaled by log2e/sqrt(32), V transposed) + fused k-norm max
template<int MODE>
__global__ __launch_bounds__(256) void gemm_bf(const short* __restrict__ A,
                                               const short* __restrict__ W,
                                               const float* __restrict__ bias,
                                               float* __restrict__ Cf,
                                               short* __restrict__ Cb,
                                               unsigned* __restrict__ kmaxp,
                                               int M, int N, int K) {
  constexpr int BM = 128, BN = 64;
  __shared__ short As[BM][72];
  __shared__ short Bs[BN][72];
  const int tid = threadIdx.x;
  const int wid = tid >> 6, lane = tid & 63;
  const int g = lane >> 4, lc = lane & 15;
  const int wr = wid >> 1, wc = wid & 1;
  const int rowBase = blockIdx.y * BM;
  const int colBase = blockIdx.x * BN;

  f32x4 acc[4][2];
#pragma unroll
  for (int m = 0; m < 4; ++m)
#pragma unroll
    for (int n = 0; n < 2; ++n) { acc[m][n][0]=0.f; acc[m][n][1]=0.f; acc[m][n][2]=0.f; acc[m][n][3]=0.f; }

  for (int k0 = 0; k0 < K; k0 += 64) {
    __syncthreads();
#pragma unroll
    for (int i = 0; i < 4; ++i) {
      int task = tid + 256 * i;
      int r = task >> 3, c = (task & 7) * 8;
      *(bf16x8*)&As[r][c] = *(const bf16x8*)(A + (size_t)(rowBase + r) * K + k0 + c);
    }
#pragma unroll
    for (int i = 0; i < 2; ++i) {
      int task = tid + 256 * i;
      int r = task >> 3, c = (task & 7) * 8;
      *(bf16x8*)&Bs[r][c] = *(const bf16x8*)(W + (size_t)(colBase + r) * K + k0 + c);
    }
    __syncthreads();
#pragma unroll
    for (int ks = 0; ks < 2; ++ks) {
      bf16x8 af[4], bfr[2];
#pragma unroll
      for (int m = 0; m < 4; ++m) af[m] = *(const bf16x8*)&As[wr*64 + m*16 + lc][ks*32 + g*8];
#pragma unroll
      for (int n = 0; n < 2; ++n) bfr[n] = *(const bf16x8*)&Bs[wc*32 + n*16 + lc][ks*32 + g*8];
#pragma unroll
      for (int m = 0; m < 4; ++m)
#pragma unroll
        for (int n = 0; n < 2; ++n)
          acc[m][n] = __builtin_amdgcn_mfma_f32_16x16x32_bf16(af[m], bfr[n], acc[m][n], 0, 0, 0);
    }
  }

  const int part = (colBase + wc * 32) >> 8;   // MODE 2: 0=Q 1=K 2=V (uniform per wave)
  float rmax = 0.f;
#pragma unroll
  for (int m = 0; m < 4; ++m) {
    float nsum[4] = {0.f, 0.f, 0.f, 0.f};
#pragma unroll
    for (int n = 0; n < 2; ++n) {
      int col = colBase + wc*32 + n*16 + lc;
      float bv = bias[col];
      int row0 = rowBase + wr*64 + m*16 + g*4;
      float vj[4];
#pragma unroll
      for (int j = 0; j < 4; ++j) vj[j] = acc[m][n][j] + bv;
      if (MODE == 1) {
#pragma unroll
        for (int j = 0; j < 4; ++j) {
          float v = vj[j];
          v = v / (1.f + __expf(-v));
          Cb[(size_t)(row0 + j) * N + col] = f2bf(v);
        }
      } else {  // MODE 2
        int h = (col >> 5) & 7;
        int hd = col & 31;
        int b = row0 >> 11, s0 = row0 & 2047;
        if (part == 2) {   // V transposed [b,h,hd,s]
          short4 s4;
          s4.x = f2bf(vj[0]); s4.y = f2bf(vj[1]); s4.z = f2bf(vj[2]); s4.w = f2bf(vj[3]);
          *(short4*)(Cb + 2 * 2097152 + (((size_t)b * 8 + h) * 32 + hd) * 2048 + s0) = s4;
        } else {
          float sc = (part == 0) ? 0.25506807f : 1.f;   // log2e / sqrt(32) folded into Q
#pragma unroll
          for (int j = 0; j < 4; ++j)
            Cb[(size_t)part * 2097152 + (((size_t)b * 8 + h) * 2048 + s0 + j) * 32 + hd] = f2bf(vj[j] * sc);
          if (part == 1) {
#pragma unroll
            for (int j = 0; j < 4; ++j) nsum[j] = fmaf(vj[j], vj[j], nsum[j]);
          }
        }
      }
    }
    if (MODE == 2 && part == 1) {
#pragma unroll
      for (int j = 0; j < 4; ++j) {
        float t = nsum[j];
        t += __shfl_xor(t, 1, 64); t += __shfl_xor(t, 2, 64);
        t += __shfl_xor(t, 4, 64); t += __shfl_xor(t, 8, 64);
        rmax = fmaxf(rmax, t);
      }
    }
  }
  if (MODE == 2 && part == 1) {
    rmax = fmaxf(rmax, __shfl_xor(rmax, 16, 64));
    rmax = fmaxf(rmax, __shfl_xor(rmax, 32, 64));
    if (lane == 0) {
      int h = ((colBase + wc * 32) >> 5) & 7;
      int b = rowBase >> 11;
      atomicMax(kmaxp + b * 8 + h, __float_as_uint(rmax));
    }
  }
}

// ---------------- bf16 MFMA GEMM, BM=64, BN=64 (f32 out)
__global__ __launch_bounds__(256) void gemm_bf64(const short* __restrict__ A,
                                                 const short* __restrict__ W,
                                                 const float* __restrict__ bias,
                                                 float* __restrict__ Cf,
                                                 int M, int N, int K) {
  __shared__ short As[64][72];
  __shared__ short Bs[64][72];
  const int tid = threadIdx.x;
  const int wid = tid >> 6, lane = tid & 63;
  const int g = lane >> 4, lc = lane & 15;
  const int wr = wid >> 1, wc = wid & 1;
  const int rowBase = blockIdx.y * 64;
  const int colBase = blockIdx.x * 64;

  f32x4 acc[2][2];
#pragma unroll
  for (int m = 0; m < 2; ++m)
#pragma unroll
    for (int n = 0; n < 2; ++n) { acc[m][n][0]=0.f; acc[m][n][1]=0.f; acc[m][n][2]=0.f; acc[m][n][3]=0.f; }

  for (int k0 = 0; k0 < K; k0 += 64) {
    __syncthreads();
#pragma unroll
    for (int i = 0; i < 2; ++i) {
      int task = tid + 256 * i;
      int r = task >> 3, c = (task & 7) * 8;
      *(bf16x8*)&As[r][c] = *(const bf16x8*)(A + (size_t)(rowBase + r) * K + k0 + c);
      *(bf16x8*)&Bs[r][c] = *(const bf16x8*)(W + (size_t)(colBase + r) * K + k0 + c);
    }
    __syncthreads();
#pragma unroll
    for (int ks = 0; ks < 2; ++ks) {
      bf16x8 af[2], bfr[2];
#pragma unroll
      for (int m = 0; m < 2; ++m) af[m] = *(const bf16x8*)&As[wr*32 + m*16 + lc][ks*32 + g*8];
#pragma unroll
      for (int n = 0; n < 2; ++n) bfr[n] = *(const bf16x8*)&Bs[wc*32 + n*16 + lc][ks*32 + g*8];
#pragma unroll
      for (int m = 0; m < 2; ++m)
#pragma unroll
        for (int n = 0; n < 2; ++n)
          acc[m][n] = __builtin_amdgcn_mfma_f32_16x16x32_bf16(af[m], bfr[n], acc[m][n], 0, 0, 0);
    }
  }

#pragma unroll
  for (int m = 0; m < 2; ++m)
#pragma unroll
    for (int n = 0; n < 2; ++n) {
      int col = colBase + wc*32 + n*16 + lc;
      float bv = bias[col];
      int row0 = rowBase + wr*32 + m*16 + g*4;
#pragma unroll
      for (int j = 0; j < 4; ++j)
        Cf[(size_t)(row0 + j) * N + col] = acc[m][n][j] + bv;
    }
}

// ---------------- MFMA flash attention: fixed-max, swizzled Ks, r5-proven LDS-P PV path
// grid: 32 qt * 8 h * 4 b = 1024 blocks, 256 threads (4 waves x 16 q-rows)
__global__ __launch_bounds__(256, 4) void attn_mfma(const short* __restrict__ qbf,
                                                    const short* __restrict__ kbf,
                                                    const short* __restrict__ vtbf,
                                                    const float* __restrict__ cutoff,
                                                    const unsigned* __restrict__ kmaxp,
                                                    short* __restrict__ outbf) {
  constexpr int KB = 64;
  const int qt = blockIdx.x & 31;
  const int h  = (blockIdx.x >> 5) & 7;
  const int b  = blockIdx.x >> 8;
  const int tid = threadIdx.x;
  const int wid = tid >> 6, lane = tid & 63;
  const int g = lane >> 4, lc = lane & 15;

  // Ks[64][32]: 64B rows, 16B-chunk slot = c ^ ((r>>1)&3) -> conflict-free write & read
  __shared__ __align__(16) short Ks[2][KB][32];
  __shared__ __align__(16) short Vt[2][HD_][72];   // V^T, r5 layout (144B stride)
  __shared__ __align__(16) short Pq[4][16][72];    // per-wave P, q-major (r5 layout)

  const int bh = b * H_ + h;
  const int qrow = qt * 64 + wid * 16 + lc;
  const short* qg = qbf + (size_t)bh * S_ * HD_;
  const short* kg = kbf + (size_t)bh * S_ * HD_;
  const short* vg = vtbf + (size_t)bh * HD_ * S_;

  bf16x8 qf = *(const bf16x8*)(qg + (size_t)qrow * HD_ + g * 8);

  // m = |q_hat| * max_k |k|  (log2 units; Q pre-scaled by log2e/sqrt(32))
  float ssq = 0.f;
#pragma unroll
  for (int i = 0; i < 8; ++i) { float f = bf2f(qf[i]); ssq = fmaf(f, f, ssq); }
  ssq += __shfl_xor(ssq, 16, 64);
  ssq += __shfl_xor(ssq, 32, 64);
  const float m = sqrtf(ssq * __uint_as_float(kmaxp[bh]));

  f32x4 oacc[2];
#pragma unroll
  for (int d = 0; d < 2; ++d) { oacc[d][0]=0.f; oacc[d][1]=0.f; oacc[d][2]=0.f; oacc[d][3]=0.f; }
  float sml = 0.f;

  const float* cb = cutoff + ((size_t)(b * S_) + qrow) * (size_t)S_;

  // staging geometry
  const int kr = tid >> 2;                           // K row 0..63
  const int kslot = ((tid & 3) ^ ((kr >> 1) & 3)) * 8;
  const short* kptr = kg + (size_t)kr * HD_ + (tid & 3) * 8;
  const int vr = tid >> 3;                           // V^T row 0..31
  const int vc = (tid & 7) * 8;
  const short* vptr = vg + (size_t)vr * S_ + vc;

  // prologue: stage tile 0
  bf16x8 kreg = *(const bf16x8*)kptr;
  bf16x8 vreg = *(const bf16x8*)vptr;
  *(bf16x8*)&Ks[0][kr][kslot] = kreg;
  *(bf16x8*)&Vt[0][vr][vc] = vreg;
  float4 cv[4];
#pragma unroll
  for (int t = 0; t < 4; ++t) cv[t] = *(const float4*)(cb + t * 16 + g * 4);
  __syncthreads();

  int cur = 0;
#pragma unroll 2
  for (int kt = 0; kt < S_; kt += KB) {
    const bool notlast = (kt + KB < S_);
    if (notlast) {
      kreg = *(const bf16x8*)(kptr + (size_t)(kt + KB) * HD_);
      vreg = *(const bf16x8*)(vptr + (kt + KB));
    }

    // S^T = mfma(K, Q): col = q = lc, row = k-local = 4g+j
    bf16x8 kf[4];
#pragma unroll
    for (int t = 0; t < 4; ++t)
      kf[t] = *(const bf16x8*)&Ks[cur][t*16 + lc][(g ^ ((lc >> 1) & 3)) * 8];
    f32x4 st[4];
#pragma unroll
    for (int t = 0; t < 4; ++t) {
      f32x4 z = {0.f, 0.f, 0.f, 0.f};
      st[t] = __builtin_amdgcn_mfma_f32_16x16x32_bf16(kf[t], qf, z, 0, 0, 0);
    }

    float4 cvn[4];
    if (notlast) {
#pragma unroll
      for (int t = 0; t < 4; ++t) cvn[t] = *(const float4*)(cb + kt + KB + t * 16 + g * 4);
    }

    // p = c * exp2(min(s - m, 8)): clamp converts any score corruption to finite error
#pragma unroll
    for (int t = 0; t < 4; ++t) {
      float p0 = cv[t].x * exp2v(fminf(st[t][0] - m, 8.f));
      float p1 = cv[t].y * exp2v(fminf(st[t][1] - m, 8.f));
      float p2 = cv[t].z * exp2v(fminf(st[t][2] - m, 8.f));
      float p3 = cv[t].w * exp2v(fminf(st[t][3] - m, 8.f));
      sml += (p0 + p1) + (p2 + p3);
      uint2 pk;
      pk.x = cvt_pk_bf16(p0, p1);
      pk.y = cvt_pk_bf16(p2, p3);
      *(uint2*)&Pq[wid][lc][t*16 + g*4] = pk;
    }

    asm volatile("s_waitcnt lgkmcnt(0)" ::: "memory");
    __builtin_amdgcn_sched_barrier(0);

    // O^T = mfma(V^T, P): K=32, proven r5 path
#pragma unroll
    for (int kh = 0; kh < 2; ++kh) {
      bf16x8 pb = *(const bf16x8*)&Pq[wid][lc][kh*32 + g*8];
#pragma unroll
      for (int dh = 0; dh < 2; ++dh) {
        bf16x8 va = *(const bf16x8*)&Vt[cur][dh*16 + lc][kh*32 + g*8];
        oacc[dh] = __builtin_amdgcn_mfma_f32_16x16x32_bf16(va, pb, oacc[dh], 0, 0, 0);
      }
    }

    if (notlast) {
      __syncthreads();
      *(bf16x8*)&Ks[cur ^ 1][kr][kslot] = kreg;
      *(bf16x8*)&Vt[cur ^ 1][vr][vc] = vreg;
      __syncthreads();
      cur ^= 1;
#pragma unroll
      for (int t = 0; t < 4; ++t) cv[t] = cvn[t];
    }
  }

  float s = sml;
  s += __shfl_xor(s, 16, 64);
  s += __shfl_xor(s, 32, 64);
  float inv = 1.f / s;
#pragma unroll
  for (int dh = 0; dh < 2; ++dh) {
    uint2 pk;
    pk.x = cvt_pk_bf16(oacc[dh][0] * inv, oacc[dh][1] * inv);
    pk.y = cvt_pk_bf16(oacc[dh][2] * inv, oacc[dh][3] * inv);
    *(uint2*)(outbf + ((size_t)(b * S_) + qrow) * D_ + h * HD_ + dh * 16 + g * 4) = pk;
  }
}

// ---------------- fused residual + LayerNorm (f32 out, optional bf16 copy)
template<int WBF>
__global__ __launch_bounds__(256) void residual_ln(const float* __restrict__ xa,
                                                   const float* __restrict__ xb,
                                                   const float* __restrict__ g,
                                                   const float* __restrict__ bt,
                                                   float* __restrict__ out,
                                                   short* __restrict__ outbf) {
  const int row  = blockIdx.x * 4 + (threadIdx.x >> 6);
  const int lane = threadIdx.x & 63;
  float4 va = *(const float4*)(xa + (size_t)row * D_ + lane * 4);
  float4 vb = *(const float4*)(xb + (size_t)row * D_ + lane * 4);
  float v[4] = {va.x + vb.x, va.y + vb.y, va.z + vb.z, va.w + vb.w};
  float s = v[0] + v[1] + v[2] + v[3];
#pragma unroll
  for (int o = 32; o > 0; o >>= 1) s += __shfl_xor(s, o, 64);
  float mu = s * (1.f / D_);
  float var = 0.f;
#pragma unroll
  for (int i = 0; i < 4; ++i) { v[i] -= mu; var += v[i] * v[i]; }
#pragma unroll
  for (int o = 32; o > 0; o >>= 1) var += __shfl_xor(var, o, 64);
  float rs = rsqrtf(var * (1.f / D_) + 1e-5f);
  float4 g4 = *(const float4*)(g + lane * 4);
  float4 b4 = *(const float4*)(bt + lane * 4);
  float4 o4 = {v[0] * rs * g4.x + b4.x, v[1] * rs * g4.y + b4.y,
               v[2] * rs * g4.z + b4.z, v[3] * rs * g4.w + b4.w};
  *(float4*)(out + (size_t)row * D_ + lane * 4) = o4;
  if (WBF) {
    short4 s4; s4.x = f2bf(o4.x); s4.y = f2bf(o4.y); s4.z = f2bf(o4.z); s4.w = f2bf(o4.w);
    *(short4*)(outbf + (size_t)row * D_ + lane * 4) = s4;
  }
}

extern "C" void kernel_launch(void* const* d_in, const int* in_sizes, int n_in,
                              void* d_out, int out_size, void* d_ws, size_t ws_size,
                              hipStream_t stream) {
  const float* tokens = (const float*)d_in[0];
  const float* cutoff = (const float*)d_in[1];
  const float* Wqkv   = (const float*)d_in[2];
  const float* bqkv   = (const float*)d_in[3];
  const float* Wo     = (const float*)d_in[4];
  const float* bo     = (const float*)d_in[5];
  const float* ln1g   = (const float*)d_in[6];
  const float* ln1b   = (const float*)d_in[7];
  const float* ln2g   = (const float*)d_in[8];
  const float* ln2b   = (const float*)d_in[9];
  const float* W1     = (const float*)d_in[10];
  const float* b1     = (const float*)d_in[11];
  const float* W2     = (const float*)d_in[12];
  const float* b2     = (const float*)d_in[13];
  float* out = (float*)d_out;

  char* w = (char*)d_ws;
  const size_t MB = 1 << 20;
  short* qbf    = (short*)w;                       // [0,4MB)
  short* kbf    = qbf + 2097152;                   // [4,8MB)
  short* vtbf   = qbf + 2 * 2097152;               // [8,12MB)  V^T [b,h,hd,s]
  short* tokbf  = (short*)(w + 12 * MB);           // [12,16MB)
  short* wq_bf  = (short*)(w + 16 * MB);
  short* wo_bf  = wq_bf + 196608;
  short* w1_bf  = wo_bf + 65536;
  short* w2_bf  = w1_bf + 131072;
  short* attnbf = tokbf;                           // reuse after QKV GEMM
  float* projOut = (float*)(w + 18 * MB);          // [18,26MB)
  float* xbuf    = (float*)(w + 26 * MB);          // [26,34MB)
  unsigned* kmax = (unsigned*)(w + 34 * MB);       // 128B
  short* xbbf    = qbf;                            // reuse after attention
  short* hbbf    = kbf;
  float* mlpOut  = projOut;

  const int M = B_ * S_;

  hipMemsetAsync(kmax, 0, 128, stream);
  cvt_all<<<dim3(2560), 256, 0, stream>>>(tokens, Wqkv, Wo, W1, W2, tokbf, wq_bf, wo_bf, w1_bf, w2_bf);

  gemm_bf<2><<<dim3(12, 64), 256, 0, stream>>>(tokbf, wq_bf, bqkv, nullptr, qbf, kmax, M, 3 * D_, D_);
  attn_mfma<<<dim3(1024), 256, 0, stream>>>(qbf, kbf, vtbf, cutoff, kmax, attnbf);
  gemm_bf64<<<dim3(4, 128), 256, 0, stream>>>(attnbf, wo_bf, bo, projOut, M, D_, D_);
  residual_ln<1><<<dim3(M / 4), 256, 0, stream>>>(tokens, projOut, ln1g, ln1b, xbuf, xbbf);
  gemm_bf<1><<<dim3(8, 64), 256, 0, stream>>>(xbbf, w1_bf, b1, nullptr, hbbf, nullptr, M, DFF_, D_);
  gemm_bf64<<<dim3(4, 128), 256, 0, stream>>>(hbbf, w2_bf, b2, mlpOut, M, D_, DFF_);
  residual_ln<0><<<dim3(M / 4), 256, 0, stream>>>(xbuf, mlpOut, ln2g, ln2b, out, nullptr);
}